// Round 6
// baseline (623.988 us; speedup 1.0000x reference)
//
#include <hip/hip_runtime.h>
#include <stdint.h>

// Shapes assumed (fixed by the problem): D=300 (KP1=320), H=600 (KP2=608), D%4==0.

// ---------- helpers ----------
typedef __attribute__((ext_vector_type(8))) short short8;
typedef __attribute__((ext_vector_type(4))) short short4v;
typedef __attribute__((ext_vector_type(4))) float float4v;

__device__ inline unsigned short f2b(float f) {
  union { float f; unsigned int i; } v; v.f = f;
  unsigned int i = v.i;
  i += 0x7fffu + ((i >> 16) & 1u);   // round-to-nearest-even
  return (unsigned short)(i >> 16);
}

// async global->LDS, 16B per lane; LDS dest is wave-uniform base + lane*16
__device__ __forceinline__ void gl_lds16(const short* g, short* l) {
  __builtin_amdgcn_global_load_lds(
      (const __attribute__((address_space(1))) unsigned int*)g,
      (__attribute__((address_space(3))) unsigned int*)l,
      16, 0, 0);
}

// ---------- transpose fp32 -> bf16, zero-padded output (pad pre-zeroed by memset) ----------
__global__ void transpose_pad(const float* __restrict__ in, short* __restrict__ out,
                              int R, int C, int outStride, int total) {
  int idx = blockIdx.x * blockDim.x + threadIdx.x;
  if (idx >= total) return;
  int r = idx / C, c = idx - r * C;
  out[(size_t)c * outStride + r] = (short)f2b(in[idx]);
}

// ---------- combined edge-embedding table: w01[f0*NUM1+f1][d] = w0[f0][d]+w1[f1][d] ----------
__global__ void build_w01(const float* __restrict__ w0, const float* __restrict__ w1,
                          float* __restrict__ w01, int D, int NUM1, int total) {
  int i = blockIdx.x * blockDim.x + threadIdx.x;
  if (i >= total) return;
  int f01 = i / D, d = i - f01 * D;
  int f0 = f01 / NUM1, f1 = f01 - f0 * NUM1;
  w01[i] = w0[f0 * D + d] + w1[f1 * D + d];
}

// ---------- CSR build: count, scan, fill ----------
__global__ void count_deg(const int* __restrict__ dst, int* __restrict__ deg, int E) {
  int e = blockIdx.x * blockDim.x + threadIdx.x;
  if (e < E) atomicAdd(&deg[dst[e]], 1);
}

__global__ void scan1(const int* __restrict__ deg, int* __restrict__ offp,
                      int* __restrict__ bsum, int n) {
  __shared__ int sh[256];
  const int t = threadIdx.x;
  const int base = blockIdx.x * 1024 + t * 4;
  int v[4], s = 0;
#pragma unroll
  for (int j = 0; j < 4; ++j) { int i = base + j; v[j] = (i < n) ? deg[i] : 0; s += v[j]; }
  sh[t] = s;
  __syncthreads();
  for (int d = 1; d < 256; d <<= 1) {
    int x = (t >= d) ? sh[t - d] : 0;
    __syncthreads();
    sh[t] += x;
    __syncthreads();
  }
  int excl = (t > 0) ? sh[t - 1] : 0;
  if (t == 255) bsum[blockIdx.x] = sh[255];
#pragma unroll
  for (int j = 0; j < 4; ++j) { int i = base + j; if (i < n) offp[i] = excl; excl += v[j]; }
}

__global__ void scan2(int* __restrict__ bsum, int nb) {
  __shared__ int sh[256];
  const int t = threadIdx.x;
  sh[t] = (t < nb) ? bsum[t] : 0;
  __syncthreads();
  for (int d = 1; d < 256; d <<= 1) {
    int x = (t >= d) ? sh[t - d] : 0;
    __syncthreads();
    sh[t] += x;
    __syncthreads();
  }
  if (t < nb) bsum[t] = (t > 0) ? sh[t - 1] : 0;
}

// fill CSR with pre-gathered per-edge payload: {src, f0*NUM1+f1}
__global__ void fill_csr(const int* __restrict__ dst, const int* __restrict__ src,
                         const int* __restrict__ ef0, const int* __restrict__ ef1,
                         const int* __restrict__ offp, const int* __restrict__ bsum,
                         int* __restrict__ tmp, int2* __restrict__ ebp, int NUM1, int E) {
  int e = blockIdx.x * blockDim.x + threadIdx.x;
  if (e >= E) return;
  int dn = dst[e];
  int pos = offp[dn] + bsum[dn >> 10] + atomicAdd(&tmp[dn], 1);
  ebp[pos] = make_int2(src[e], ef0[e] * NUM1 + ef1[e]);
}

// ---------- gather: aggb[node] = sum_e (nf[src]+w01[f01]) + deg*(b0+b1), bf16 out ----------
__global__ void gather_agg(const float* __restrict__ nf, const float* __restrict__ w01,
                           const float* __restrict__ b0f, const float* __restrict__ b1f,
                           const int* __restrict__ deg, const int* __restrict__ offp,
                           const int* __restrict__ bsum, const int2* __restrict__ ebp,
                           unsigned short* __restrict__ aggb,
                           int D, int ldab, int total) {
  int idx = blockIdx.x * blockDim.x + threadIdx.x;
  if (idx >= total) return;
  const int quads = ldab >> 2;
  int node = idx / quads;
  int q = idx - node * quads;
  int d = q * 4;
  unsigned short* op = &aggb[(size_t)node * ldab + d];
  if (d >= D) {  // zero the pad columns so GEMM1's A pad is clean
    short4v z = {0, 0, 0, 0};
    *(short4v*)op = z;
    return;
  }
  int dg = deg[node];
  int o = offp[node] + bsum[node >> 10];
  float4v acc = {0.f, 0.f, 0.f, 0.f};
  for (int j = 0; j < dg; ++j) {
    int2 p = ebp[o + j];
    float4v nv = *(const float4v*)&nf[(size_t)p.x * D + d];
    float4v wv = *(const float4v*)&w01[(size_t)p.y * D + d];
    acc += nv + wv;
  }
  float4v bb = *(const float4v*)&b0f[d];
  float4v b2v = *(const float4v*)&b1f[d];
  acc += (float)dg * (bb + b2v);
  short4v r;
#pragma unroll
  for (int j = 0; j < 4; ++j) r[j] = (short)f2b(acc[j]);
  *(short4v*)op = r;
}

// ---------- MFMA GEMM: m97 geometry (128x128 tile, 2x2 waves of 64x64), gl_lds staging ----------
// A bf16 [MP][lda], MP a multiple of 128 (pad rows may be garbage: row-isolated, never stored).
// BT [BrowsAlloc][ldbt] bf16, BrowsAlloc >= ncolb*128 (pad rows zeroed).
// Source-side swizzle: LDS[row][u] holds tile-row[u ^ sw(row)], sw(r)=(r^(r>>2))&3 (16B units);
// fragment reads apply the same XOR -> ~2-way bank conflicts (free).
// Loop: R3's proven 2-barrier single-buffer structure; 16 MFMA : 8 ds_read per wave per k-step.
template<bool RELU, bool STATS, bool CF32>
__global__ __launch_bounds__(256, 3)
void gemm_lds(const short* __restrict__ A, int lda,
              const short* __restrict__ BT, int ldbt,
              const float* __restrict__ bias,
              void* __restrict__ Cv, int ldc, int storeN,
              int M, int Nn, int KP, int ncolb,
              float* __restrict__ colsum, float* __restrict__ colsumsq) {
  constexpr int BM = 128, BN = 128, BK = 32;
  __shared__ __align__(16) short Al[BM * BK];   // 8 KB, linear [row][32]
  __shared__ __align__(16) short Bl[BN * BK];   // 8 KB

  // ---- bijective XCD chunk swizzle; w = by*ncolb + bx (col fastest -> A panel shares XCD L2)
  const int nwg = gridDim.x;
  const int b = blockIdx.x;
  const int qq = nwg >> 3, rr = nwg & 7;
  const int xcd = b & 7, ii = b >> 3;
  const int w = ((xcd < rr) ? xcd * (qq + 1) : rr * (qq + 1) + (xcd - rr) * qq) + ii;
  const int by = w / ncolb, bx = w - by * ncolb;
  const int m0 = by * BM, n0 = bx * BN;

  const int t = threadIdx.x;
  const int wave = t >> 6, lane = t & 63, quad = lane >> 4, lr = lane & 15;
  const int wm = (wave >> 1) * 64, wn = (wave & 1) * 64;

  // ---- staging sources (k-invariant). Round l in {0,1}: rows (l*4+wave)*16 + lane>>2 ----
  const int au = lane & 3;
  int arow[2], brow[2];
  const short* asrc[2];
  const short* bsrc[2];
  int adst[2], bdst[2];
#pragma unroll
  for (int l = 0; l < 2; ++l) {
    int r = (l * 4 + wave) * 16 + (lane >> 2);
    int sw = au ^ ((r ^ (r >> 2)) & 3);
    arow[l] = r;
    asrc[l] = A + (size_t)(m0 + r) * lda + sw * 8;
    adst[l] = (l * 4 + wave) * 512;          // shorts; HW adds lane*16B
    brow[l] = r;
    bsrc[l] = BT + (size_t)(n0 + r) * ldbt + sw * 8;
    bdst[l] = (l * 4 + wave) * 512;
  }

  // ---- fragment read offsets (k-invariant, same XOR) ----
  int aoff[4], boff[4];
#pragma unroll
  for (int mi = 0; mi < 4; ++mi) {
    int r = wm + mi * 16 + lr;
    aoff[mi] = r * BK + (quad ^ ((r ^ (r >> 2)) & 3)) * 8;
  }
#pragma unroll
  for (int ni = 0; ni < 4; ++ni) {
    int r = wn + ni * 16 + lr;
    boff[ni] = r * BK + (quad ^ ((r ^ (r >> 2)) & 3)) * 8;
  }

  const float4v fzero = {0.f, 0.f, 0.f, 0.f};
  float4v acc[4][4];
#pragma unroll
  for (int mi = 0; mi < 4; ++mi)
#pragma unroll
    for (int ni = 0; ni < 4; ++ni) acc[mi][ni] = fzero;

  for (int k0 = 0; k0 < KP; k0 += BK) {
    __syncthreads();           // all waves done reading previous tile
    gl_lds16(asrc[0] + k0, &Al[adst[0]]);
    gl_lds16(asrc[1] + k0, &Al[adst[1]]);
    gl_lds16(bsrc[0] + k0, &Bl[bdst[0]]);
    gl_lds16(bsrc[1] + k0, &Bl[bdst[1]]);
    __syncthreads();           // drains vmcnt -> staged data visible
    short8 af[4], bfr[4];
#pragma unroll
    for (int mi = 0; mi < 4; ++mi) af[mi] = *(const short8*)&Al[aoff[mi]];
#pragma unroll
    for (int ni = 0; ni < 4; ++ni) bfr[ni] = *(const short8*)&Bl[boff[ni]];
#pragma unroll
    for (int mi = 0; mi < 4; ++mi)
#pragma unroll
      for (int ni = 0; ni < 4; ++ni)
        acc[mi][ni] = __builtin_amdgcn_mfma_f32_16x16x32_bf16(af[mi], bfr[ni], acc[mi][ni], 0, 0, 0);
  }

  // ---- epilogue: bias (+ReLU) (+column stats), store ----
#pragma unroll
  for (int ni = 0; ni < 4; ++ni) {
    int gn = n0 + wn + ni * 16 + lr;
    bool store_c = (gn < storeN);
    bool ncol = (gn < Nn);
    float bv = ncol ? bias[gn] : 0.f;
    float s = 0.f, q = 0.f;
#pragma unroll
    for (int mi = 0; mi < 4; ++mi) {
      int gmb = m0 + wm + mi * 16 + quad * 4;
#pragma unroll
      for (int r = 0; r < 4; ++r) {
        int gm = gmb + r;
        float v = acc[mi][ni][r] + bv;
        if (RELU) v = fmaxf(v, 0.f);
        if (gm < M && store_c) {
          if constexpr (CF32) ((float*)Cv)[(size_t)gm * ldc + gn] = v;
          else ((unsigned short*)Cv)[(size_t)gm * ldc + gn] = f2b(v);
          if (STATS && ncol) { s += v; q += v * v; }
        }
      }
    }
    if constexpr (STATS) {
      s += __shfl_xor(s, 16); q += __shfl_xor(q, 16);
      s += __shfl_xor(s, 32); q += __shfl_xor(q, 32);
      if (quad == 0 && ncol) {
        unsafeAtomicAdd(&colsum[gn], s);
        unsafeAtomicAdd(&colsumsq[gn], q);
      }
    }
  }
}

// ---------- BatchNorm finalize: scale/shift per column ----------
__global__ void bn_finalize(const float* __restrict__ colsum, const float* __restrict__ colsumsq,
                            const float* __restrict__ gamma, const float* __restrict__ beta,
                            float2* __restrict__ ss, int D, float invN) {
  int d = blockIdx.x * blockDim.x + threadIdx.x;
  if (d >= D) return;
  float mean = colsum[d] * invN;
  float var = fmaxf(colsumsq[d] * invN - mean * mean, 0.f);
  float sc = rsqrtf(var + 1e-5f) * gamma[d];
  float sh = beta[d] - mean * sc;
  ss[d] = make_float2(sc, sh);
}

// ---------- BatchNorm apply (in place, float4 vectorized; requires D%4==0) ----------
__global__ void bn_apply4(float4v* __restrict__ out, const float2* __restrict__ ss,
                          int total4, int cquads) {
  int idx = blockIdx.x * blockDim.x + threadIdx.x;
  if (idx >= total4) return;
  int c = (idx % cquads) * 4;
  float4v v = out[idx];
  float2 p0 = ss[c], p1 = ss[c + 1], p2 = ss[c + 2], p3 = ss[c + 3];
  v[0] = v[0] * p0.x + p0.y;
  v[1] = v[1] * p1.x + p1.y;
  v[2] = v[2] * p2.x + p2.y;
  v[3] = v[3] * p3.x + p3.y;
  out[idx] = v;
}

__global__ void bn_apply1(float* __restrict__ out, const float2* __restrict__ ss,
                          int total, int D) {
  int idx = blockIdx.x * blockDim.x + threadIdx.x;
  if (idx >= total) return;
  float2 p = ss[idx % D];
  out[idx] = out[idx] * p.x + p.y;
}

// ---------- launch ----------
extern "C" void kernel_launch(void* const* d_in, const int* in_sizes, int n_in,
                              void* d_out, int out_size, void* d_ws, size_t ws_size,
                              hipStream_t stream) {
  const float* nf  = (const float*)d_in[0];
  const int*   src = (const int*)d_in[1];
  const int*   dst = (const int*)d_in[2];
  const int*   ef0 = (const int*)d_in[3];
  const int*   ef1 = (const int*)d_in[4];
  const float* ew0 = (const float*)d_in[5];
  const float* eb0 = (const float*)d_in[6];
  const float* ew1 = (const float*)d_in[7];
  const float* eb1 = (const float*)d_in[8];
  const float* w1  = (const float*)d_in[9];
  const float* b1  = (const float*)d_in[10];
  const float* w2  = (const float*)d_in[11];
  const float* b2  = (const float*)d_in[12];
  const float* gam = (const float*)d_in[13];
  const float* bet = (const float*)d_in[14];

  const int D = in_sizes[13];          // 300
  const int N = in_sizes[0] / D;       // 100000
  const int E = in_sizes[1];           // 200000
  const int H = in_sizes[10];          // 600
  const int NUM0 = in_sizes[5] / D;    // 6
  const int NUM1 = in_sizes[7] / D;    // 3
  const int KP1 = (D + 31) / 32 * 32;  // 320
  const int KP2 = (H + 31) / 32 * 32;  // 608
  const int NCB1 = (H + 127) / 128;    // 5 col blocks, covers 640
  const int NCB2 = (D + 127) / 128;    // 3 col blocks, covers 384
  const int BROWS1 = NCB1 * 128;       // 640 rows allocated for wT1
  const int BROWS2 = NCB2 * 128;       // 384 rows allocated for wT2
  const int nrowb = (N + 127) / 128;   // 782
  const int MP = nrowb * 128;          // 100096 padded A rows
  const int nb  = (N + 1023) / 1024;   // scan blocks (<=256)

  char* ws = (char*)d_ws;
  size_t off = 0;
  // ---- zeroed region ----
  float* colsum   = (float*)(ws + off); off += 4096;
  float* colsumsq = (float*)(ws + off); off += 4096;
  short* wT1      = (short*)(ws + off); off += (size_t)BROWS1 * KP1 * 2;
  short* wT2      = (short*)(ws + off); off += (size_t)BROWS2 * KP2 * 2;
  int*   deg      = (int*)(ws + off);   off += (size_t)N * 4;
  int*   tmp      = (int*)(ws + off);   off += (size_t)N * 4;
  size_t zero_bytes = off;
  // ---- uninitialized region ----
  float2* ss      = (float2*)(ws + off); off += 4096;
  float* w01      = (float*)(ws + off);  off += (size_t)NUM0 * NUM1 * D * 4;
  int*   offp     = (int*)(ws + off);    off += (size_t)N * 4;
  int*   bsum     = (int*)(ws + off);    off += 4096;
  int2*  ebp      = (int2*)(ws + off);   off += (size_t)E * 8;
  unsigned short* aggb = (unsigned short*)(ws + off); off += (size_t)MP * KP1 * 2;
  short* h1       = (short*)(ws + off);  off += (size_t)MP * KP2 * 2;

  hipMemsetAsync(d_ws, 0, zero_bytes, stream);

  {  // w1: (D x H) fp32 -> wT1: (H rows x KP1 cols) bf16
    int tot = D * H;
    transpose_pad<<<(tot + 255) / 256, 256, 0, stream>>>(w1, wT1, D, H, KP1, tot);
  }
  {  // w2: (H x D) fp32 -> wT2: (D rows x KP2 cols) bf16
    int tot = H * D;
    transpose_pad<<<(tot + 255) / 256, 256, 0, stream>>>(w2, wT2, H, D, KP2, tot);
  }
  {  // combined edge-embedding table
    int tot = NUM0 * NUM1 * D;
    build_w01<<<(tot + 255) / 256, 256, 0, stream>>>(ew0, ew1, w01, D, NUM1, tot);
  }
  // ---- CSR build ----
  count_deg<<<(E + 255) / 256, 256, 0, stream>>>(dst, deg, E);
  scan1<<<nb, 256, 0, stream>>>(deg, offp, bsum, N);
  scan2<<<1, 256, 0, stream>>>(bsum, nb);
  fill_csr<<<(E + 255) / 256, 256, 0, stream>>>(dst, src, ef0, ef1, offp, bsum, tmp,
                                                ebp, NUM1, E);
  // ---- gather (atomic-free aggregation, bf16 out) ----
  {
    int total = N * (KP1 / 4);
    gather_agg<<<(total + 255) / 256, 256, 0, stream>>>(
        nf, w01, eb0, eb1, deg, offp, bsum, ebp, aggb, D, KP1, total);
  }
  {  // h1 = relu(aggb @ w1 + b1), bf16, stride KP2; true zeros in cols [H, KP2)
    gemm_lds<true, false, false><<<nrowb * NCB1, 256, 0, stream>>>(
        (const short*)aggb, KP1, wT1, KP1, b1,
        h1, KP2, KP2, N, H, KP1, NCB1, nullptr, nullptr);
  }
  {  // h = h1 @ w2 + b2 (+ column stats), fp32 out
    gemm_lds<false, true, true><<<nrowb * NCB2, 256, 0, stream>>>(
        h1, KP2, wT2, KP2, b2,
        d_out, D, D, N, D, KP2, NCB2, colsum, colsumsq);
  }
  bn_finalize<<<(D + 255) / 256, 256, 0, stream>>>(colsum, colsumsq, gam, bet, ss, D,
                                                   1.0f / (float)N);
  if ((D & 3) == 0) {
    int total4 = N * (D / 4);
    bn_apply4<<<(total4 + 255) / 256, 256, 0, stream>>>((float4v*)d_out, ss, total4, D / 4);
  } else {
    int tot = N * D;
    bn_apply1<<<(tot + 255) / 256, 256, 0, stream>>>((float*)d_out, ss, tot, D);
  }
}

// Round 7
// 546.437 us; speedup vs baseline: 1.1419x; 1.1419x over previous
//
#include <hip/hip_runtime.h>
#include <stdint.h>

// Shapes assumed (fixed by the problem): D=300 (KP1=320), H=600 (KP2=608), D%4==0.

// ---------- helpers ----------
typedef __attribute__((ext_vector_type(8))) short short8;
typedef __attribute__((ext_vector_type(4))) short short4v;
typedef __attribute__((ext_vector_type(4))) float float4v;

__device__ inline float b2f(unsigned short u) {
  union { unsigned int i; float f; } v; v.i = ((unsigned int)u) << 16; return v.f;
}
__device__ inline unsigned short f2b(float f) {
  union { float f; unsigned int i; } v; v.f = f;
  unsigned int i = v.i;
  i += 0x7fffu + ((i >> 16) & 1u);   // round-to-nearest-even
  return (unsigned short)(i >> 16);
}

// async global->LDS, 16B per lane; LDS dest is wave-uniform base + lane*16
__device__ __forceinline__ void gl_lds16(const short* g, short* l) {
  __builtin_amdgcn_global_load_lds(
      (const __attribute__((address_space(1))) unsigned int*)g,
      (__attribute__((address_space(3))) unsigned int*)l,
      16, 0, 0);
}

// ---------- transpose fp32 -> bf16, zero-padded output (pad pre-zeroed by memset) ----------
__global__ void transpose_pad(const float* __restrict__ in, short* __restrict__ out,
                              int R, int C, int outStride, int total) {
  int idx = blockIdx.x * blockDim.x + threadIdx.x;
  if (idx >= total) return;
  int r = idx / C, c = idx - r * C;
  out[(size_t)c * outStride + r] = (short)f2b(in[idx]);
}

// ---------- nf fp32 -> bf16, rows padded to ldab cols with zeros (requires D%4==0) ----------
__global__ void nf2b(const float* __restrict__ nf, unsigned short* __restrict__ nfb,
                     int D, int ldab, int total) {
  int idx = blockIdx.x * blockDim.x + threadIdx.x;
  if (idx >= total) return;
  const int chunks = ldab >> 3;
  int node = idx / chunks, c = idx - node * chunks;
  int d = c * 8;
  short4v r0 = {0, 0, 0, 0}, r1 = {0, 0, 0, 0};
  const float* p = &nf[(size_t)node * D + d];
  if (d + 3 < D) {
    float4v v = *(const float4v*)p;
    r0[0] = (short)f2b(v[0]); r0[1] = (short)f2b(v[1]);
    r0[2] = (short)f2b(v[2]); r0[3] = (short)f2b(v[3]);
  }
  if (d + 7 < D) {
    float4v v = *(const float4v*)(p + 4);
    r1[0] = (short)f2b(v[0]); r1[1] = (short)f2b(v[1]);
    r1[2] = (short)f2b(v[2]); r1[3] = (short)f2b(v[3]);
  }
  unsigned short* op = &nfb[(size_t)node * ldab + d];
  *(short4v*)op = r0;
  *(short4v*)(op + 4) = r1;
}

// ---------- combined edge table (bf16, padded) + combined bias (fp32, padded) ----------
// w01b[f0*NUM1+f1][d] = bf16(w0[f0][d]+w1[f1][d]) for d<D else 0;  bb01[d] = b0[d]+b1[d] (pad 0)
__global__ void build_w01b(const float* __restrict__ w0, const float* __restrict__ w1,
                           const float* __restrict__ b0, const float* __restrict__ b1,
                           unsigned short* __restrict__ w01b, float* __restrict__ bb01,
                           int D, int NUM1, int ldab, int total) {
  int i = blockIdx.x * blockDim.x + threadIdx.x;
  if (i >= total) return;
  int f01 = i / ldab, d = i - f01 * ldab;
  int f0 = f01 / NUM1, f1 = f01 - f0 * NUM1;
  float v = (d < D) ? (w0[f0 * D + d] + w1[f1 * D + d]) : 0.f;
  w01b[i] = f2b(v);
  if (f01 == 0) bb01[d] = (d < D) ? (b0[d] + b1[d]) : 0.f;
}

// ---------- CSR build: count, scan, fill ----------
__global__ void count_deg(const int* __restrict__ dst, int* __restrict__ deg, int E) {
  int e = blockIdx.x * blockDim.x + threadIdx.x;
  if (e < E) atomicAdd(&deg[dst[e]], 1);
}

__global__ void scan1(const int* __restrict__ deg, int* __restrict__ offp,
                      int* __restrict__ bsum, int n) {
  __shared__ int sh[256];
  const int t = threadIdx.x;
  const int base = blockIdx.x * 1024 + t * 4;
  int v[4], s = 0;
#pragma unroll
  for (int j = 0; j < 4; ++j) { int i = base + j; v[j] = (i < n) ? deg[i] : 0; s += v[j]; }
  sh[t] = s;
  __syncthreads();
  for (int d = 1; d < 256; d <<= 1) {
    int x = (t >= d) ? sh[t - d] : 0;
    __syncthreads();
    sh[t] += x;
    __syncthreads();
  }
  int excl = (t > 0) ? sh[t - 1] : 0;
  if (t == 255) bsum[blockIdx.x] = sh[255];
#pragma unroll
  for (int j = 0; j < 4; ++j) { int i = base + j; if (i < n) offp[i] = excl; excl += v[j]; }
}

__global__ void scan2(int* __restrict__ bsum, int nb) {
  __shared__ int sh[256];
  const int t = threadIdx.x;
  sh[t] = (t < nb) ? bsum[t] : 0;
  __syncthreads();
  for (int d = 1; d < 256; d <<= 1) {
    int x = (t >= d) ? sh[t - d] : 0;
    __syncthreads();
    sh[t] += x;
    __syncthreads();
  }
  if (t < nb) bsum[t] = (t > 0) ? sh[t - 1] : 0;
}

// fill CSR with pre-gathered per-edge payload: {src, f0*NUM1+f1}
__global__ void fill_csr(const int* __restrict__ dst, const int* __restrict__ src,
                         const int* __restrict__ ef0, const int* __restrict__ ef1,
                         const int* __restrict__ offp, const int* __restrict__ bsum,
                         int* __restrict__ tmp, int2* __restrict__ ebp, int NUM1, int E) {
  int e = blockIdx.x * blockDim.x + threadIdx.x;
  if (e >= E) return;
  int dn = dst[e];
  int pos = offp[dn] + bsum[dn >> 10] + atomicAdd(&tmp[dn], 1);
  ebp[pos] = make_int2(src[e], ef0[e] * NUM1 + ef1[e]);
}

// ---------- gather (bf16 inputs): aggb[node] = sum_e (nfb[src]+w01b[f01]) + deg*bb01 ----------
// All inputs padded to ldab cols with zeros -> pad columns compute to exact 0, no branches.
__global__ void gather_agg(const unsigned short* __restrict__ nfb,
                           const unsigned short* __restrict__ w01b,
                           const float* __restrict__ bb01,
                           const int* __restrict__ deg, const int* __restrict__ offp,
                           const int* __restrict__ bsum, const int2* __restrict__ ebp,
                           unsigned short* __restrict__ aggb,
                           int ldab, int total) {
  int idx = blockIdx.x * blockDim.x + threadIdx.x;
  if (idx >= total) return;
  const int chunks = ldab >> 3;
  int node = idx / chunks;
  int c = idx - node * chunks;
  int d = c * 8;
  int dg = deg[node];
  int o = offp[node] + bsum[node >> 10];
  float acc[8] = {0.f, 0.f, 0.f, 0.f, 0.f, 0.f, 0.f, 0.f};
  for (int j = 0; j < dg; ++j) {
    int2 p = ebp[o + j];
    short8 nv = *(const short8*)&nfb[(size_t)p.x * ldab + d];
    short8 wv = *(const short8*)&w01b[(size_t)p.y * ldab + d];
#pragma unroll
    for (int k = 0; k < 8; ++k)
      acc[k] += b2f((unsigned short)nv[k]) + b2f((unsigned short)wv[k]);
  }
  float4v bb0 = *(const float4v*)&bb01[d];
  float4v bb1 = *(const float4v*)&bb01[d + 4];
  float fdg = (float)dg;
#pragma unroll
  for (int k = 0; k < 4; ++k) { acc[k] += fdg * bb0[k]; acc[k + 4] += fdg * bb1[k]; }
  short8 r;
#pragma unroll
  for (int k = 0; k < 8; ++k) r[k] = (short)f2b(acc[k]);
  *(short8*)&aggb[(size_t)node * ldab + d] = r;
}

// ---------- MFMA GEMM: global_load_lds staging, XOR-swizzled linear LDS, XCD-swizzled ----------
// R3-exact configuration (measured 127-130 us per GEMM).
// A bf16 [MP][lda], MP a multiple of 128 (pad rows may be garbage: row-isolated, never stored).
// BT [BrowsAlloc][ldbt] bf16; grid cols * 64 must be <= BT row allocation.
// Source-side swizzle: LDS[row][u] holds A[row][u ^ sw(row)], sw(r)=(r^(r>>2))&3 (16B units);
// fragment reads apply the same XOR -> 2-way bank conflicts (free).
template<bool RELU, bool STATS, bool CF32>
__global__ __launch_bounds__(256, 6)
void gemm_lds(const short* __restrict__ A, int lda,
              const short* __restrict__ BT, int ldbt,
              const float* __restrict__ bias,
              void* __restrict__ Cv, int ldc, int storeN,
              int M, int Nn, int KP, int ncolb,
              float* __restrict__ colsum, float* __restrict__ colsumsq) {
  constexpr int BM = 128, BN = 64, BK = 32;
  __shared__ __align__(16) short Al[BM * BK];   // 8 KB, linear [row][32]
  __shared__ __align__(16) short Bl[BN * BK];   // 4 KB

  // ---- bijective XCD chunk swizzle; w = by*ncolb + bx (col fastest -> A panel shares XCD L2)
  const int nwg = gridDim.x;
  const int b = blockIdx.x;
  const int qq = nwg >> 3, rr = nwg & 7;
  const int xcd = b & 7, ii = b >> 3;
  const int w = ((xcd < rr) ? xcd * (qq + 1) : rr * (qq + 1) + (xcd - rr) * qq) + ii;
  const int by = w / ncolb, bx = w - by * ncolb;
  const int m0 = by * BM, n0 = bx * BN;

  const int t = threadIdx.x;
  const int wave = t >> 6, lane = t & 63, quad = lane >> 4, lr = lane & 15;
  const int wm = (wave >> 1) * 64, wn = (wave & 1) * 32;

  // ---- staging sources (k-invariant): dest byte = roundbase + lane*16 ----
  const int au = lane & 3;
  const int arow0 = (wave * 2 + 0) * 16 + (lane >> 2);
  const int arow1 = (wave * 2 + 1) * 16 + (lane >> 2);
  const int asw0 = au ^ ((arow0 ^ (arow0 >> 2)) & 3);
  const int asw1 = au ^ ((arow1 ^ (arow1 >> 2)) & 3);
  const short* asrc0 = A + (size_t)(m0 + arow0) * lda + asw0 * 8;
  const short* asrc1 = A + (size_t)(m0 + arow1) * lda + asw1 * 8;
  short* adst0 = &Al[(wave * 2 + 0) * 512];
  short* adst1 = &Al[(wave * 2 + 1) * 512];
  const int brow = wave * 16 + (lane >> 2);
  const int bsw = au ^ ((brow ^ (brow >> 2)) & 3);
  const short* bsrc = BT + (size_t)(n0 + brow) * ldbt + bsw * 8;
  short* bdst = &Bl[wave * 512];

  // ---- fragment read offsets (k-invariant, same XOR) ----
  int aoff[4], boff[2];
#pragma unroll
  for (int mi = 0; mi < 4; ++mi) {
    int r = wm + mi * 16 + lr;
    aoff[mi] = r * BK + (quad ^ ((r ^ (r >> 2)) & 3)) * 8;
  }
#pragma unroll
  for (int ni = 0; ni < 2; ++ni) {
    int r = wn + ni * 16 + lr;
    boff[ni] = r * BK + (quad ^ ((r ^ (r >> 2)) & 3)) * 8;
  }

  const float4v fzero = {0.f, 0.f, 0.f, 0.f};
  float4v acc[4][2];
#pragma unroll
  for (int mi = 0; mi < 4; ++mi) {
    acc[mi][0] = fzero; acc[mi][1] = fzero;
  }

  for (int k0 = 0; k0 < KP; k0 += BK) {
    __syncthreads();           // previous iteration's LDS reads complete
    gl_lds16(asrc0 + k0, adst0);
    gl_lds16(asrc1 + k0, adst1);
    gl_lds16(bsrc + k0, bdst);
    __syncthreads();           // drains vmcnt -> staged data visible
    short8 af[4], bfr[2];
#pragma unroll
    for (int mi = 0; mi < 4; ++mi) af[mi] = *(const short8*)&Al[aoff[mi]];
#pragma unroll
    for (int ni = 0; ni < 2; ++ni) bfr[ni] = *(const short8*)&Bl[boff[ni]];
#pragma unroll
    for (int mi = 0; mi < 4; ++mi) {
      acc[mi][0] = __builtin_amdgcn_mfma_f32_16x16x32_bf16(af[mi], bfr[0], acc[mi][0], 0, 0, 0);
      acc[mi][1] = __builtin_amdgcn_mfma_f32_16x16x32_bf16(af[mi], bfr[1], acc[mi][1], 0, 0, 0);
    }
  }

  // ---- epilogue: bias (+ReLU) (+column stats), store ----
#pragma unroll
  for (int ni = 0; ni < 2; ++ni) {
    int gn = n0 + wn + ni * 16 + lr;
    bool store_c = (gn < storeN);
    bool ncol = (gn < Nn);
    float bv = ncol ? bias[gn] : 0.f;
    float s = 0.f, q = 0.f;
#pragma unroll
    for (int mi = 0; mi < 4; ++mi) {
      int gmb = m0 + wm + mi * 16 + quad * 4;
#pragma unroll
      for (int r = 0; r < 4; ++r) {
        int gm = gmb + r;
        float v = acc[mi][ni][r] + bv;
        if (RELU) v = fmaxf(v, 0.f);
        if (gm < M && store_c) {
          if constexpr (CF32) ((float*)Cv)[(size_t)gm * ldc + gn] = v;
          else ((unsigned short*)Cv)[(size_t)gm * ldc + gn] = f2b(v);
          if (STATS && ncol) { s += v; q += v * v; }
        }
      }
    }
    if constexpr (STATS) {
      s += __shfl_xor(s, 16); q += __shfl_xor(q, 16);
      s += __shfl_xor(s, 32); q += __shfl_xor(q, 32);
      if (quad == 0 && ncol) {
        unsafeAtomicAdd(&colsum[gn], s);
        unsafeAtomicAdd(&colsumsq[gn], q);
      }
    }
  }
}

// ---------- BatchNorm finalize: scale/shift per column ----------
__global__ void bn_finalize(const float* __restrict__ colsum, const float* __restrict__ colsumsq,
                            const float* __restrict__ gamma, const float* __restrict__ beta,
                            float2* __restrict__ ss, int D, float invN) {
  int d = blockIdx.x * blockDim.x + threadIdx.x;
  if (d >= D) return;
  float mean = colsum[d] * invN;
  float var = fmaxf(colsumsq[d] * invN - mean * mean, 0.f);
  float sc = rsqrtf(var + 1e-5f) * gamma[d];
  float sh = beta[d] - mean * sc;
  ss[d] = make_float2(sc, sh);
}

// ---------- BatchNorm apply (in place, float4 vectorized; requires D%4==0) ----------
__global__ void bn_apply4(float4v* __restrict__ out, const float2* __restrict__ ss,
                          int total4, int cquads) {
  int idx = blockIdx.x * blockDim.x + threadIdx.x;
  if (idx >= total4) return;
  int c = (idx % cquads) * 4;
  float4v v = out[idx];
  float2 p0 = ss[c], p1 = ss[c + 1], p2 = ss[c + 2], p3 = ss[c + 3];
  v[0] = v[0] * p0.x + p0.y;
  v[1] = v[1] * p1.x + p1.y;
  v[2] = v[2] * p2.x + p2.y;
  v[3] = v[3] * p3.x + p3.y;
  out[idx] = v;
}

__global__ void bn_apply1(float* __restrict__ out, const float2* __restrict__ ss,
                          int total, int D) {
  int idx = blockIdx.x * blockDim.x + threadIdx.x;
  if (idx >= total) return;
  float2 p = ss[idx % D];
  out[idx] = out[idx] * p.x + p.y;
}

// ---------- launch ----------
extern "C" void kernel_launch(void* const* d_in, const int* in_sizes, int n_in,
                              void* d_out, int out_size, void* d_ws, size_t ws_size,
                              hipStream_t stream) {
  const float* nf  = (const float*)d_in[0];
  const int*   src = (const int*)d_in[1];
  const int*   dst = (const int*)d_in[2];
  const int*   ef0 = (const int*)d_in[3];
  const int*   ef1 = (const int*)d_in[4];
  const float* ew0 = (const float*)d_in[5];
  const float* eb0 = (const float*)d_in[6];
  const float* ew1 = (const float*)d_in[7];
  const float* eb1 = (const float*)d_in[8];
  const float* w1  = (const float*)d_in[9];
  const float* b1  = (const float*)d_in[10];
  const float* w2  = (const float*)d_in[11];
  const float* b2  = (const float*)d_in[12];
  const float* gam = (const float*)d_in[13];
  const float* bet = (const float*)d_in[14];

  const int D = in_sizes[13];          // 300
  const int N = in_sizes[0] / D;       // 100000
  const int E = in_sizes[1];           // 200000
  const int H = in_sizes[10];          // 600
  const int NUM0 = in_sizes[5] / D;    // 6
  const int NUM1 = in_sizes[7] / D;    // 3
  const int KP1 = (D + 31) / 32 * 32;  // 320
  const int KP2 = (H + 31) / 32 * 32;  // 608
  const int NCB1 = (H + 63) / 64;      // 10 col blocks, covers 640
  const int NCB2 = (D + 63) / 64;      // 5 col blocks, covers 320
  const int BROWS1 = NCB1 * 64;        // 640 rows allocated for wT1
  const int BROWS2 = NCB2 * 64;        // 320 rows allocated for wT2
  const int nrowb = (N + 127) / 128;   // 782
  const int MP = nrowb * 128;          // 100096 padded A rows
  const int nb  = (N + 1023) / 1024;   // scan blocks (<=256)

  char* ws = (char*)d_ws;
  size_t off = 0;
  // ---- zeroed region ----
  float* colsum   = (float*)(ws + off); off += 4096;
  float* colsumsq = (float*)(ws + off); off += 4096;
  short* wT1      = (short*)(ws + off); off += (size_t)BROWS1 * KP1 * 2;
  short* wT2      = (short*)(ws + off); off += (size_t)BROWS2 * KP2 * 2;
  int*   deg      = (int*)(ws + off);   off += (size_t)N * 4;
  int*   tmp      = (int*)(ws + off);   off += (size_t)N * 4;
  size_t zero_bytes = off;
  // ---- uninitialized region ----
  float2* ss      = (float2*)(ws + off); off += 4096;
  unsigned short* w01b = (unsigned short*)(ws + off); off += (size_t)NUM0 * NUM1 * KP1 * 2;
  float* bb01     = (float*)(ws + off);  off += (size_t)KP1 * 4;
  int*   offp     = (int*)(ws + off);    off += (size_t)N * 4;
  int*   bsum     = (int*)(ws + off);    off += 4096;
  int2*  ebp      = (int2*)(ws + off);   off += (size_t)E * 8;
  unsigned short* aggb = (unsigned short*)(ws + off); off += (size_t)MP * KP1 * 2;
  short* h1       = (short*)(ws + off);  off += (size_t)MP * KP2 * 2;
  // nfb (N x KP1 bf16, 64 MB) overlays h1 (122 MB): gather finishes before GEMM1 writes h1
  unsigned short* nfb = (unsigned short*)h1;

  hipMemsetAsync(d_ws, 0, zero_bytes, stream);

  {  // w1: (D x H) fp32 -> wT1: (H rows x KP1 cols) bf16
    int tot = D * H;
    transpose_pad<<<(tot + 255) / 256, 256, 0, stream>>>(w1, wT1, D, H, KP1, tot);
  }
  {  // w2: (H x D) fp32 -> wT2: (D rows x KP2 cols) bf16
    int tot = H * D;
    transpose_pad<<<(tot + 255) / 256, 256, 0, stream>>>(w2, wT2, H, D, KP2, tot);
  }
  {  // combined edge-embedding table (bf16, padded) + combined bias (fp32, padded)
    int tot = NUM0 * NUM1 * KP1;
    build_w01b<<<(tot + 255) / 256, 256, 0, stream>>>(ew0, ew1, eb0, eb1,
                                                      w01b, bb01, D, NUM1, KP1, tot);
  }
  {  // node feats fp32 -> bf16 padded
    int tot = N * (KP1 / 8);
    nf2b<<<(tot + 255) / 256, 256, 0, stream>>>(nf, nfb, D, KP1, tot);
  }
  // ---- CSR build ----
  count_deg<<<(E + 255) / 256, 256, 0, stream>>>(dst, deg, E);
  scan1<<<nb, 256, 0, stream>>>(deg, offp, bsum, N);
  scan2<<<1, 256, 0, stream>>>(bsum, nb);
  fill_csr<<<(E + 255) / 256, 256, 0, stream>>>(dst, src, ef0, ef1, offp, bsum, tmp,
                                                ebp, NUM1, E);
  // ---- gather (atomic-free aggregation, bf16 in/out) ----
  {
    int total = N * (KP1 / 8);
    gather_agg<<<(total + 255) / 256, 256, 0, stream>>>(
        nfb, w01b, bb01, deg, offp, bsum, ebp, aggb, KP1, total);
  }
  {  // h1 = relu(aggb @ w1 + b1), bf16, stride KP2; true zeros in cols [H, KP2)
    gemm_lds<true, false, false><<<nrowb * NCB1, 256, 0, stream>>>(
        (const short*)aggb, KP1, wT1, KP1, b1,
        h1, KP2, KP2, N, H, KP1, NCB1, nullptr, nullptr);
  }
  {  // h = h1 @ w2 + b2 (+ column stats), fp32 out
    gemm_lds<false, true, true><<<nrowb * NCB2, 256, 0, stream>>>(
        h1, KP2, wT2, KP2, b2,
        d_out, D, D, N, D, KP2, NCB2, colsum, colsumsq);
  }
  bn_finalize<<<(D + 255) / 256, 256, 0, stream>>>(colsum, colsumsq, gam, bet, ss, D,
                                                   1.0f / (float)N);
  if ((D & 3) == 0) {
    int total4 = N * (D / 4);
    bn_apply4<<<(total4 + 255) / 256, 256, 0, stream>>>((float4v*)d_out, ss, total4, D / 4);
  } else {
    int tot = N * D;
    bn_apply1<<<(tot + 255) / 256, 256, 0, stream>>>((float*)d_out, ss, tot, D);
  }
}